// Round 12
// baseline (2531.879 us; speedup 1.0000x reference)
//
#include <hip/hip_runtime.h>
#include <hip/hip_bf16.h>
#include <cstdint>

typedef __bf16 bf16x8 __attribute__((ext_vector_type(8)));
typedef float f32x4 __attribute__((ext_vector_type(4)));
typedef float f32x16 __attribute__((ext_vector_type(16)));
typedef unsigned short u16t;

__device__ __forceinline__ u16t f2bf(float f) {
    uint32_t u = __builtin_bit_cast(uint32_t, f);
    u += 0x7FFF + ((u >> 16) & 1);
    return (u16t)(u >> 16);
}

// Problem constants
constexpr int Bb = 4, Ss = 2048, Dd = 1024, Hh = 16;
constexpr int Mrows = Bb * Ss;   // 8192
constexpr float NEG = -1e30f;
constexpr float QSCALE = 0.125f * 1.44269504088896340736f;  // 1/sqrt(64) * log2(e)

// ---------------- convert x (fp32 -> bf16) ----------------
__global__ __launch_bounds__(256) void cvt_bf16(const float* __restrict__ in,
                                                u16t* __restrict__ out, int n) {
    int i = (blockIdx.x * 256 + threadIdx.x) * 4;
    if (i >= n) return;
    float4 v = *(const float4*)(in + i);
    u16t o[4] = {f2bf(v.x), f2bf(v.y), f2bf(v.z), f2bf(v.w)};
    *(ushort4*)(out + i) = *(ushort4*)o;
}

// -------- transpose + convert weights: Wq/Wk/Wv -> concatenated [3072][1024], Wo -> [1024][1024] --------
__global__ __launch_bounds__(256) void transpose_cvt4(const float* __restrict__ W0,
                                                      const float* __restrict__ W1,
                                                      const float* __restrict__ W2,
                                                      const float* __restrict__ W3,
                                                      u16t* __restrict__ Tqkv,
                                                      u16t* __restrict__ To) {
    __shared__ float tile[64][65];
    int z = blockIdx.z;
    const float* W = z == 0 ? W0 : z == 1 ? W1 : z == 2 ? W2 : W3;
    u16t* WT = z < 3 ? Tqkv + (size_t)z * Dd * Dd : To;
    int n0 = blockIdx.x * 64, k0 = blockIdx.y * 64;
    int c = threadIdx.x & 63, r0 = (threadIdx.x >> 6) * 16;
    for (int i = 0; i < 16; i++)
        tile[c][r0 + i] = W[(size_t)(k0 + r0 + i) * Dd + n0 + c];
    __syncthreads();
    for (int i = 0; i < 16; i++)
        WT[(size_t)(n0 + r0 + i) * Dd + k0 + c] = f2bf(tile[r0 + i][c]);
}

// ============ 3-buffer counted-vmcnt GEMM core (BM=128, BN=256, BK=64, 512 thr) ============
#define GEMM_CORE_512(A_, BT_, m0_, n0_)                                                    \
    __shared__ __align__(16) u16t Asm3[3][128 * 64];                                        \
    __shared__ __align__(16) u16t Bsm3[3][256 * 64];                                        \
    int tid = threadIdx.x, lane = tid & 63, w = tid >> 6;                                   \
    int wm = w >> 2, wn = w & 3;                                                            \
    int ln = lane & 15, g = lane >> 4;                                                      \
    int l3 = lane >> 3, l7 = lane & 7;                                                      \
    int swz = (l7 ^ (l3 & 7)) * 8;                                                          \
    const u16t* Ap[2]; int Ao[2];                                                           \
    _Pragma("unroll")                                                                       \
    for (int ii = 0; ii < 2; ii++) {                                                        \
        int rg = m0_ + ii * 64 + w * 8 + l3;                                                \
        Ap[ii] = A_ + (size_t)rg * Dd + swz;                                                \
        Ao[ii] = ii * 4096 + w * 512;                                                       \
    }                                                                                       \
    const u16t* Bp[4]; int Bo[4];                                                           \
    _Pragma("unroll")                                                                       \
    for (int ii = 0; ii < 4; ii++) {                                                        \
        int rg = n0_ + ii * 64 + w * 8 + l3;                                                \
        Bp[ii] = BT_ + (size_t)rg * Dd + swz;                                               \
        Bo[ii] = ii * 4096 + w * 512;                                                       \
    }                                                                                       \
    auto stage = [&](int buf, int t) {                                                      \
        int k0 = t * 64;                                                                    \
        _Pragma("unroll")                                                                   \
        for (int ii = 0; ii < 2; ii++)                                                      \
            __builtin_amdgcn_global_load_lds(Ap[ii] + k0, &Asm3[buf][Ao[ii]], 16, 0, 0);    \
        _Pragma("unroll")                                                                   \
        for (int ii = 0; ii < 4; ii++)                                                      \
            __builtin_amdgcn_global_load_lds(Bp[ii] + k0, &Bsm3[buf][Bo[ii]], 16, 0, 0);    \
    };                                                                                      \
    f32x4 acc[4][4] = {};                                                                   \
    int coff[2] = {((g) ^ (ln & 7)) * 8, ((4 + g) ^ (ln & 7)) * 8};                         \
    int arow = wm * 64 + ln;                                                                \
    int brow = wn * 64 + ln;                                                                \
    auto compute = [&](int buf) {                                                           \
        bf16x8 af[4][2], bfr[4][2];                                                         \
        _Pragma("unroll")                                                                   \
        for (int i = 0; i < 4; i++)                                                         \
            _Pragma("unroll")                                                               \
            for (int ks = 0; ks < 2; ks++)                                                  \
                af[i][ks] = *(const bf16x8*)&Asm3[buf][(arow + i * 16) * 64 + coff[ks]];    \
        _Pragma("unroll")                                                                   \
        for (int j = 0; j < 4; j++)                                                         \
            _Pragma("unroll")                                                               \
            for (int ks = 0; ks < 2; ks++)                                                  \
                bfr[j][ks] = *(const bf16x8*)&Bsm3[buf][(brow + j * 16) * 64 + coff[ks]];   \
        _Pragma("unroll")                                                                   \
        for (int i = 0; i < 4; i++)                                                         \
            _Pragma("unroll")                                                               \
            for (int j = 0; j < 4; j++) {                                                   \
                acc[i][j] = __builtin_amdgcn_mfma_f32_16x16x32_bf16(af[i][0], bfr[j][0],    \
                                                                    acc[i][j], 0, 0, 0);    \
                acc[i][j] = __builtin_amdgcn_mfma_f32_16x16x32_bf16(af[i][1], bfr[j][1],    \
                                                                    acc[i][j], 0, 0, 0);    \
            }                                                                               \
    };                                                                                      \
    stage(0, 0);                                                                            \
    stage(1, 1);                                                                            \
    for (int t = 0; t < 14; t++) {                                                          \
        asm volatile("s_barrier" ::: "memory");                                             \
        stage((t + 2) % 3, t + 2);                                                          \
        asm volatile("s_waitcnt vmcnt(12)" ::: "memory");                                   \
        compute(t % 3);                                                                     \
    }                                                                                       \
    asm volatile("s_barrier" ::: "memory");                                                 \
    asm volatile("s_waitcnt vmcnt(6)" ::: "memory");                                        \
    compute(14 % 3);                                                                        \
    asm volatile("s_barrier" ::: "memory");                                                 \
    asm volatile("s_waitcnt vmcnt(0)" ::: "memory");                                        \
    compute(15 % 3);

// ---------------- fused QKV GEMM: [8192 x 3072], segmented epilogue ----------------
__global__ __launch_bounds__(512) void gemm_qkv(const u16t* __restrict__ A,
                                                const u16t* __restrict__ BT,
                                                const float* __restrict__ bq,
                                                const float* __restrict__ bk,
                                                const float* __restrict__ bvv,
                                                u16t* __restrict__ Qh,
                                                u16t* __restrict__ Kh,
                                                u16t* __restrict__ Vt) {
    int bid = blockIdx.x;                        // 768 blocks (64 m x 12 n), tail-free
    int wg = (bid & 7) * 96 + (bid >> 3);        // bijective XCD swizzle (768 % 8 == 0)
    int m0 = (wg / 12) * 128, n0 = (wg % 12) * 256;

    GEMM_CORE_512(A, BT, m0, n0)

    #pragma unroll
    for (int i = 0; i < 4; i++) {
        #pragma unroll
        for (int j = 0; j < 4; j++) {
            int col = n0 + wn * 64 + j * 16 + ln;
            int seg = col >> 10, c1k = col & 1023;
            float bias = seg == 0 ? bq[c1k] : seg == 1 ? bk[c1k] : bvv[c1k];
            int rowb = m0 + wm * 64 + i * 16 + g * 4;
            int b = rowb >> 11, s = rowb & 2047, h = c1k >> 6, hd = c1k & 63;
            if (seg == 0) {
                for (int r = 0; r < 4; r++) {
                    float v = (acc[i][j][r] + bias) * QSCALE;
                    Qh[((size_t)(b * Hh + h) * Ss + s + r) * 64 + hd] = f2bf(v);
                }
            } else if (seg == 1) {
                for (int r = 0; r < 4; r++)
                    Kh[((size_t)(b * Hh + h) * Ss + s + r) * 64 + hd] = f2bf(acc[i][j][r] + bias);
            } else {
                u16t pk4[4];
                for (int r = 0; r < 4; r++) pk4[r] = f2bf(acc[i][j][r] + bias);
                *(ushort4*)(Vt + ((size_t)((b * Hh + h) * 64 + hd) << 11) + s) = *(ushort4*)pk4;
            }
        }
    }
}

// ---------------- output GEMM: d_out[8192 x 1024] fp32 ----------------
__global__ __launch_bounds__(512) void gemm_o(const u16t* __restrict__ A,
                                              const u16t* __restrict__ BT,
                                              const float* __restrict__ bias,
                                              float* __restrict__ outF) {
    int bid = blockIdx.x;                        // 256 blocks (64 m x 4 n), tail-free
    int wg = (bid & 7) * 32 + (bid >> 3);
    int m0 = (wg >> 2) * 128, n0 = (wg & 3) * 256;

    GEMM_CORE_512(A, BT, m0, n0)

    #pragma unroll
    for (int i = 0; i < 4; i++) {
        #pragma unroll
        for (int j = 0; j < 4; j++) {
            int col = n0 + wn * 64 + j * 16 + ln;
            float bv = bias[col];
            int rowb = m0 + wm * 64 + i * 16 + g * 4;
            for (int r = 0; r < 4; r++)
                outF[(size_t)(rowb + r) * Dd + col] = acc[i][j][r] + bv;
        }
    }
}

// ---------------- Flash attention: 8 waves, in-block kv-split, LDS merge ----------------
// Block handles q-tiles (ip, 15-ip) sequentially. Per task (q-tile qx): wave-group 0
// (waves 0-3) scans kv tiles [0, qx], group 1 (waves 4-7) scans [qx+1, 2qx+1] — equal
// halves, uniform barriers. Each group has its own K/V double buffer (64KB total ->
// 2 blocks/CU -> 16 waves/CU). Group 1 posts unnormalized O/m/l into the dead K-buffer
// region; group 0 combines and writes. No HBM partials, no merge kernel.
__global__ __launch_bounds__(512, 4) void attn(const u16t* __restrict__ Qh,
                                               const u16t* __restrict__ Kh,
                                               const u16t* __restrict__ Vt,
                                               u16t* __restrict__ Ob) {
    __shared__ __align__(16) u16t Ksm[2][2][64 * 64];   // [group][buf] 32KB
    __shared__ __align__(16) u16t Vsm[2][2][64 * 64];   // [group][buf] 32KB
    float*  mergeO  = (float*)&Ksm[0][0][0];            // 32KB alias (dead after scan)
    float2* mergeML = (float2*)&Vsm[0][0][0];           // 1KB alias

    int tid = threadIdx.x, lane = tid & 63, w = tid >> 6;
    int grp = w >> 2, wg = w & 3;
    int l31 = lane & 31, hi = lane >> 5;
    // XCD-clustered: 512 blocks; XCD x hosts bh in [8x, 8x+8)
    int flat = blockIdx.y * 8 + blockIdx.x;
    int xcd = flat & 7, jj = flat >> 3;
    int bh = xcd * 8 + (jj >> 3);
    int ip = jj & 7;

    const u16t* Kb = Kh + (size_t)bh * Ss * 64;
    const u16t* Vb = Vt + (size_t)bh * 64 * Ss;

    // staging (per group, 4 waves): issue i of wave wg covers rows wg*16+i*8..+7 linearly.
    // slot (r, c) holds src[r][c ^ swz(r)], swz(r) = (r&7) ^ ((r>>3)&3)
    int sr0 = wg * 16 + (lane >> 3);
    int sr1 = sr0 + 8;
    int sc0 = (((lane & 7) ^ (sr0 & 7) ^ ((sr0 >> 3) & 3)) * 8);
    int sc1 = (((lane & 7) ^ (sr1 & 7) ^ ((sr1 >> 3) & 3)) * 8);
    const u16t* Kg0 = Kb + (size_t)sr0 * 64 + sc0;
    const u16t* Kg1 = Kb + (size_t)sr1 * 64 + sc1;
    const u16t* Vg0 = Vb + (size_t)sr0 * Ss + sc0;
    const u16t* Vg1 = Vb + (size_t)sr1 * Ss + sc1;

    auto stage = [&](int buf, int t) {
        size_t koff = (size_t)t * 64 * 64;
        size_t voff = (size_t)t * 64;
        __builtin_amdgcn_global_load_lds(Kg0 + koff, &Ksm[grp][buf][(wg * 2 + 0) * 512], 16, 0, 0);
        __builtin_amdgcn_global_load_lds(Kg1 + koff, &Ksm[grp][buf][(wg * 2 + 1) * 512], 16, 0, 0);
        __builtin_amdgcn_global_load_lds(Vg0 + voff, &Vsm[grp][buf][(wg * 2 + 0) * 512], 16, 0, 0);
        __builtin_amdgcn_global_load_lds(Vg1 + voff, &Vsm[grp][buf][(wg * 2 + 1) * 512], 16, 0, 0);
    };

    int swzr = (l31 & 7) ^ ((l31 >> 3) & 3);   // same key for rows l31, 32+l31

    for (int task = 0; task < 2; task++) {
        int qx = task == 0 ? ip : 15 - ip;
        int qb = qx * 128;
        int q0w = qb + wg * 32;
        int qlane = q0w + l31;

        bf16x8 qB[4];
        {
            const u16t* Qp = Qh + ((size_t)bh * Ss + qlane) * 64 + hi * 8;
            #pragma unroll
            for (int ks = 0; ks < 4; ks++)
                qB[ks] = *(const bf16x8*)(Qp + 16 * ks);
        }

        f32x16 oacc[2] = {};
        float m_run = NEG, l_run = 0.f;
        int half = qx + 1;
        int tbase = grp == 0 ? 0 : half;

        stage(0, tbase);
        __syncthreads();

        for (int it = 0; it < half; it++) {
            int cur = it & 1;
            int kv0 = (tbase + it) << 6;
            if (it + 1 < half) stage(cur ^ 1, tbase + it + 1);

            bool active = (kv0 <= q0w + 31);
            if (active) {
                // ---- QK^T (swapped): lane owns one q-column of S^T ----
                f32x16 p0 = {}, p1 = {};
                __builtin_amdgcn_s_setprio(1);
                #pragma unroll
                for (int ks = 0; ks < 4; ks++) {
                    int cc = (2 * ks + hi) ^ swzr;
                    bf16x8 ka0 = *(const bf16x8*)&Ksm[grp][cur][(size_t)l31 * 64 + cc * 8];
                    bf16x8 ka1 = *(const bf16x8*)&Ksm[grp][cur][(size_t)(32 + l31) * 64 + cc * 8];
                    p0 = __builtin_amdgcn_mfma_f32_32x32x16_bf16(ka0, qB[ks], p0, 0, 0, 0);
                    p1 = __builtin_amdgcn_mfma_f32_32x32x16_bf16(ka1, qB[ks], p1, 0, 0, 0);
                }
                __builtin_amdgcn_s_setprio(0);

                if (kv0 + 63 > q0w) {               // causal mask, diagonal tiles only
                    #pragma unroll
                    for (int r = 0; r < 16; r++) {
                        int kvg = kv0 + (r & 3) + 8 * (r >> 2) + 4 * hi;
                        if (kvg > qlane)      p0[r] = NEG;
                        if (kvg + 32 > qlane) p1[r] = NEG;
                    }
                }

                // ---- online softmax, defer-max (THR=10, exp2 domain) ----
                float ma = fmaxf(p0[0], p1[0]), mb = fmaxf(p0[1], p1[1]);
                float mc = fmaxf(p0[2], p1[2]), md = fmaxf(p0[3], p1[3]);
                #pragma unroll
                for (int r = 4; r < 16; r += 4) {
                    ma = fmaxf(ma, fmaxf(p0[r], p1[r]));
                    mb = fmaxf(mb, fmaxf(p0[r + 1], p1[r + 1]));
                    mc = fmaxf(mc, fmaxf(p0[r + 2], p1[r + 2]));
                    md = fmaxf(md, fmaxf(p0[r + 3], p1[r + 3]));
                }
                float mt = fmaxf(fmaxf(ma, mb), fmaxf(mc, md));
                mt = fmaxf(mt, __shfl_xor(mt, 32));
                if (__any(mt > m_run + 10.0f)) {
                    float mn = fmaxf(m_run, mt);
                    float al = __builtin_exp2f(m_run - mn);
                    m_run = mn;
                    l_run *= al;
                    #pragma unroll
                    for (int r = 0; r < 16; r++) { oacc[0][r] *= al; oacc[1][r] *= al; }
                }
                #pragma unroll
                for (int r = 0; r < 16; r++) {
                    p0[r] = __builtin_exp2f(p0[r] - m_run);
                    p1[r] = __builtin_exp2f(p1[r] - m_run);
                }
                float sa = 0.f, sb = 0.f, sc2 = 0.f, sd = 0.f;
                #pragma unroll
                for (int r = 0; r < 16; r += 4) {
                    sa += p0[r] + p1[r];
                    sb += p0[r + 1] + p1[r + 1];
                    sc2 += p0[r + 2] + p1[r + 2];
                    sd += p0[r + 3] + p1[r + 3];
                }
                float rsum = (sa + sb) + (sc2 + sd);
                rsum += __shfl_xor(rsum, 32);
                l_run += rsum;

                // ---- pack P -> PV B-fragments: 16 cvt_pk + 8 permlane32_swap ----
                bf16x8 pb[4];
                {
                    uint32_t c0, c1, c2, c3;
                    asm("v_cvt_pk_bf16_f32 %0, %1, %2" : "=v"(c0) : "v"(p0[0]), "v"(p0[1]));
                    asm("v_cvt_pk_bf16_f32 %0, %1, %2" : "=v"(c1) : "v"(p0[2]), "v"(p0[3]));
                    asm("v_cvt_pk_bf16_f32 %0, %1, %2" : "=v"(c2) : "v"(p0[4]), "v"(p0[5]));
                    asm("v_cvt_pk_bf16_f32 %0, %1, %2" : "=v"(c3) : "v"(p0[6]), "v"(p0[7]));
                    asm volatile("v_permlane32_swap_b32 %0, %1" : "+v"(c0), "+v"(c2));
                    asm volatile("v_permlane32_swap_b32 %0, %1" : "+v"(c1), "+v"(c3));
                    uint32_t w4[4] = {c0, c1, c2, c3};
                    pb[0] = *(bf16x8*)w4;
                    uint32_t d0, d1, d2, d3;
                    asm("v_cvt_pk_bf16_f32 %0, %1, %2" : "=v"(d0) : "v"(p0[8]),  "v"(p0[9]));
                    asm("v_cvt_pk_bf16_f32 %0, %1, %2" : "=v"(d1) : "v"(p0[10]), "v"(p0[11]));
                    asm("v_cvt_pk_bf16_f32 %0, %1, %2" : "=v"(d2) : "v"(p0[12]), "v"(p0[13]));
                    asm("v_cvt_pk_bf16_f32 %0, %1, %2" : "=v"(d3) : "v"(p0[14]), "v"(p0[15]));
                    asm volatile("v_permlane32_swap_b32 %0, %1" : "+v"(d0), "+v"(d2));
                    asm volatile("v_permlane32_swap_b32 %0, %1" : "+v"(d1), "+v"(d3));
                    uint32_t w5[4] = {d0, d1, d2, d3};
                    pb[1] = *(bf16x8*)w5;
                    uint32_t e0, e1, e2, e3;
                    asm("v_cvt_pk_bf16_f32 %0, %1, %2" : "=v"(e0) : "v"(p1[0]), "v"(p1[1]));
                    asm("v_cvt_pk_bf16_f32 %0, %1, %2" : "=v"(e1) : "v"(p1[2]), "v"(p1[3]));
                    asm("v_cvt_pk_bf16_f32 %0, %1, %2" : "=v"(e2) : "v"(p1[4]), "v"(p1[5]));
                    asm("v_cvt_pk_bf16_f32 %0, %1, %2" : "=v"(e3) : "v"(p1[6]), "v"(p1[7]));
                    asm volatile("v_permlane32_swap_b32 %0, %1" : "+v"(e0), "+v"(e2));
                    asm volatile("v_permlane32_swap_b32 %0, %1" : "+v"(e1), "+v"(e3));
                    uint32_t w6[4] = {e0, e1, e2, e3};
                    pb[2] = *(bf16x8*)w6;
                    uint32_t f0, f1, f2, f3;
                    asm("v_cvt_pk_bf16_f32 %0, %1, %2" : "=v"(f0) : "v"(p1[8]),  "v"(p1[9]));
                    asm("v_cvt_pk_bf16_f32 %0, %1, %2" : "=v"(f1) : "v"(p1[10]), "v"(p1[11]));
                    asm("v_cvt_pk_bf16_f32 %0, %1, %2" : "=v"(f2) : "v"(p1[12]), "v"(p1[13]));
                    asm("v_cvt_pk_bf16_f32 %0, %1, %2" : "=v"(f3) : "v"(p1[14]), "v"(p1[15]));
                    asm volatile("v_permlane32_swap_b32 %0, %1" : "+v"(f0), "+v"(f2));
                    asm volatile("v_permlane32_swap_b32 %0, %1" : "+v"(f1), "+v"(f3));
                    uint32_t w7[4] = {f0, f1, f2, f3};
                    pb[3] = *(bf16x8*)w7;
                }

                // ---- PV (swapped): O^T[d][q] += V^T[d][kv] @ P^T[kv][q] ----
                __builtin_amdgcn_s_setprio(1);
                #pragma unroll
                for (int dt = 0; dt < 2; dt++) {
                    int drow = dt * 32 + l31;
                    #pragma unroll
                    for (int ks = 0; ks < 4; ks++) {
                        int cc = (2 * ks + hi) ^ swzr;
                        bf16x8 va = *(const bf16x8*)&Vsm[grp][cur][(size_t)drow * 64 + cc * 8];
                        oacc[dt] = __builtin_amdgcn_mfma_f32_32x32x16_bf16(va, pb[ks], oacc[dt], 0, 0, 0);
                    }
                }
                __builtin_amdgcn_s_setprio(0);
            }
            __syncthreads();
        }

        // ---- merge: group 1 posts partials into dead K/V LDS ----
        if (grp == 1) {
            if (hi == 0) {
                float2 v; v.x = m_run; v.y = l_run;
                mergeML[wg * 32 + l31] = v;
            }
            #pragma unroll
            for (int fidx = 0; fidx < 8; fidx++) {
                int fq = (fidx + l31) & 7;          // rotated order: conflict-free banks
                int dt = fq >> 2, rb = (fq & 3) * 4;
                f32x4 ch;
                #pragma unroll
                for (int j = 0; j < 4; j++) ch[j] = oacc[dt][rb + j];
                *(f32x4*)(mergeO + ((size_t)(wg * 512 + l31 * 16 + hi * 8 + fq) << 2)) = ch;
            }
        }
        __syncthreads();

        if (grp == 0) {
            float2 ml1 = mergeML[wg * 32 + l31];
            float mmax = fmaxf(m_run, ml1.x);
            float e0 = __builtin_exp2f(m_run - mmax);
            float e1 = __builtin_exp2f(ml1.x - mmax);
            float linv = 1.0f / (l_run * e0 + ml1.y * e1);
            float f0 = e0 * linv, f1 = e1 * linv;
            #pragma unroll
            for (int fidx = 0; fidx < 8; fidx++) {
                int fq = (fidx + l31) & 7;
                f32x4 c1 = *(const f32x4*)(mergeO + ((size_t)(wg * 512 + l31 * 16 + hi * 8 + fq) << 2));
                int dt = fq >> 2, rb = (fq & 3) * 4;
                #pragma unroll
                for (int j = 0; j < 4; j++)
                    oacc[dt][rb + j] = oacc[dt][rb + j] * f0 + c1[j] * f1;
            }
        }
        __syncthreads();   // merge reads done before next task restages LDS

        if (grp == 0) {
            int b = bh >> 4, h = bh & 15;
            u16t* Op = Ob + ((size_t)(b * Ss + qlane)) * Dd + h * 64;
            #pragma unroll
            for (int dt = 0; dt < 2; dt++)
                #pragma unroll
                for (int rq = 0; rq < 4; rq++) {
                    u16t pk4[4];
                    #pragma unroll
                    for (int j = 0; j < 4; j++) pk4[j] = f2bf(oacc[dt][rq * 4 + j]);
                    int d0 = dt * 32 + rq * 8 + hi * 4;
                    *(ushort4*)(Op + d0) = *(ushort4*)pk4;
                }
        }
    }
}

extern "C" void kernel_launch(void* const* d_in, const int* in_sizes, int n_in,
                              void* d_out, int out_size, void* d_ws, size_t ws_size,
                              hipStream_t stream) {
    const float* x  = (const float*)d_in[0];
    const float* Wq = (const float*)d_in[1];
    const float* bq = (const float*)d_in[2];
    const float* Wk = (const float*)d_in[3];
    const float* bk = (const float*)d_in[4];
    const float* Wv = (const float*)d_in[5];
    const float* bv = (const float*)d_in[6];
    const float* Wo = (const float*)d_in[7];
    const float* bo = (const float*)d_in[8];

    char* ws = (char*)d_ws;
    size_t off = 0;
    auto alloc = [&](size_t bytes) { char* p = ws + off; off += (bytes + 255) & ~(size_t)255; return p; };
    u16t* xb    = (u16t*)alloc((size_t)Mrows * Dd * 2);
    u16t* WqkvT = (u16t*)alloc((size_t)3 * Dd * Dd * 2);
    u16t* WoT   = (u16t*)alloc((size_t)Dd * Dd * 2);
    u16t* Qh    = (u16t*)alloc((size_t)Mrows * Dd * 2);
    u16t* Kh    = (u16t*)alloc((size_t)Mrows * Dd * 2);
    u16t* Vtp   = (u16t*)alloc((size_t)Mrows * Dd * 2);
    u16t* Ob    = (u16t*)alloc((size_t)Mrows * Dd * 2);

    int nx = Mrows * Dd;
    cvt_bf16<<<nx / (256 * 4), 256, 0, stream>>>(x, xb, nx);
    dim3 tg(16, 16, 4);
    transpose_cvt4<<<tg, 256, 0, stream>>>(Wq, Wk, Wv, Wo, WqkvT, WoT);

    gemm_qkv<<<768, 512, 0, stream>>>(xb, WqkvT, bq, bk, bv, Qh, Kh, Vtp);

    dim3 ga(8, Bb * Hh);              // 512 blocks x 8 waves, in-block kv-split
    attn<<<ga, 512, 0, stream>>>(Qh, Kh, Vtp, Ob);

    gemm_o<<<256, 512, 0, stream>>>(Ob, WoT, bo, (float*)d_out);
}

// Round 13
// 192.106 us; speedup vs baseline: 13.1796x; 13.1796x over previous
//
#include <hip/hip_runtime.h>
#include <hip/hip_bf16.h>
#include <cstdint>

typedef __bf16 bf16x8 __attribute__((ext_vector_type(8)));
typedef float f32x4 __attribute__((ext_vector_type(4)));
typedef float f32x16 __attribute__((ext_vector_type(16)));
typedef unsigned short u16t;

__device__ __forceinline__ u16t f2bf(float f) {
    uint32_t u = __builtin_bit_cast(uint32_t, f);
    u += 0x7FFF + ((u >> 16) & 1);
    return (u16t)(u >> 16);
}

// Problem constants
constexpr int Bb = 4, Ss = 2048, Dd = 1024, Hh = 16;
constexpr int Mrows = Bb * Ss;   // 8192
constexpr float NEG = -1e30f;
constexpr float QSCALE = 0.125f * 1.44269504088896340736f;  // 1/sqrt(64) * log2(e)

// ---------------- convert x (fp32 -> bf16) ----------------
__global__ __launch_bounds__(256) void cvt_bf16(const float* __restrict__ in,
                                                u16t* __restrict__ out, int n) {
    int i = (blockIdx.x * 256 + threadIdx.x) * 4;
    if (i >= n) return;
    float4 v = *(const float4*)(in + i);
    u16t o[4] = {f2bf(v.x), f2bf(v.y), f2bf(v.z), f2bf(v.w)};
    *(ushort4*)(out + i) = *(ushort4*)o;
}

// -------- transpose + convert weights: Wq/Wk/Wv -> concatenated [3072][1024], Wo -> [1024][1024] --------
__global__ __launch_bounds__(256) void transpose_cvt4(const float* __restrict__ W0,
                                                      const float* __restrict__ W1,
                                                      const float* __restrict__ W2,
                                                      const float* __restrict__ W3,
                                                      u16t* __restrict__ Tqkv,
                                                      u16t* __restrict__ To) {
    __shared__ float tile[64][65];
    int z = blockIdx.z;
    const float* W = z == 0 ? W0 : z == 1 ? W1 : z == 2 ? W2 : W3;
    u16t* WT = z < 3 ? Tqkv + (size_t)z * Dd * Dd : To;
    int n0 = blockIdx.x * 64, k0 = blockIdx.y * 64;
    int c = threadIdx.x & 63, r0 = (threadIdx.x >> 6) * 16;
    for (int i = 0; i < 16; i++)
        tile[c][r0 + i] = W[(size_t)(k0 + r0 + i) * Dd + n0 + c];
    __syncthreads();
    for (int i = 0; i < 16; i++)
        WT[(size_t)(n0 + r0 + i) * Dd + k0 + c] = f2bf(tile[r0 + i][c]);
}

// ============ 3-buffer counted-vmcnt GEMM core (BM=128, BN=256, BK=64, 512 thr) ============
#define GEMM_CORE_512(A_, BT_, m0_, n0_)                                                    \
    __shared__ __align__(16) u16t Asm3[3][128 * 64];                                        \
    __shared__ __align__(16) u16t Bsm3[3][256 * 64];                                        \
    int tid = threadIdx.x, lane = tid & 63, w = tid >> 6;                                   \
    int wm = w >> 2, wn = w & 3;                                                            \
    int ln = lane & 15, g = lane >> 4;                                                      \
    int l3 = lane >> 3, l7 = lane & 7;                                                      \
    int swz = (l7 ^ (l3 & 7)) * 8;                                                          \
    const u16t* Ap[2]; int Ao[2];                                                           \
    _Pragma("unroll")                                                                       \
    for (int ii = 0; ii < 2; ii++) {                                                        \
        int rg = m0_ + ii * 64 + w * 8 + l3;                                                \
        Ap[ii] = A_ + (size_t)rg * Dd + swz;                                                \
        Ao[ii] = ii * 4096 + w * 512;                                                       \
    }                                                                                       \
    const u16t* Bp[4]; int Bo[4];                                                           \
    _Pragma("unroll")                                                                       \
    for (int ii = 0; ii < 4; ii++) {                                                        \
        int rg = n0_ + ii * 64 + w * 8 + l3;                                                \
        Bp[ii] = BT_ + (size_t)rg * Dd + swz;                                               \
        Bo[ii] = ii * 4096 + w * 512;                                                       \
    }                                                                                       \
    auto stage = [&](int buf, int t) {                                                      \
        int k0 = t * 64;                                                                    \
        _Pragma("unroll")                                                                   \
        for (int ii = 0; ii < 2; ii++)                                                      \
            __builtin_amdgcn_global_load_lds(Ap[ii] + k0, &Asm3[buf][Ao[ii]], 16, 0, 0);    \
        _Pragma("unroll")                                                                   \
        for (int ii = 0; ii < 4; ii++)                                                      \
            __builtin_amdgcn_global_load_lds(Bp[ii] + k0, &Bsm3[buf][Bo[ii]], 16, 0, 0);    \
    };                                                                                      \
    f32x4 acc[4][4] = {};                                                                   \
    int coff[2] = {((g) ^ (ln & 7)) * 8, ((4 + g) ^ (ln & 7)) * 8};                         \
    int arow = wm * 64 + ln;                                                                \
    int brow = wn * 64 + ln;                                                                \
    auto compute = [&](int buf) {                                                           \
        bf16x8 af[4][2], bfr[4][2];                                                         \
        _Pragma("unroll")                                                                   \
        for (int i = 0; i < 4; i++)                                                         \
            _Pragma("unroll")                                                               \
            for (int ks = 0; ks < 2; ks++)                                                  \
                af[i][ks] = *(const bf16x8*)&Asm3[buf][(arow + i * 16) * 64 + coff[ks]];    \
        _Pragma("unroll")                                                                   \
        for (int j = 0; j < 4; j++)                                                         \
            _Pragma("unroll")                                                               \
            for (int ks = 0; ks < 2; ks++)                                                  \
                bfr[j][ks] = *(const bf16x8*)&Bsm3[buf][(brow + j * 16) * 64 + coff[ks]];   \
        _Pragma("unroll")                                                                   \
        for (int i = 0; i < 4; i++)                                                         \
            _Pragma("unroll")                                                               \
            for (int j = 0; j < 4; j++) {                                                   \
                acc[i][j] = __builtin_amdgcn_mfma_f32_16x16x32_bf16(af[i][0], bfr[j][0],    \
                                                                    acc[i][j], 0, 0, 0);    \
                acc[i][j] = __builtin_amdgcn_mfma_f32_16x16x32_bf16(af[i][1], bfr[j][1],    \
                                                                    acc[i][j], 0, 0, 0);    \
            }                                                                               \
    };                                                                                      \
    stage(0, 0);                                                                            \
    stage(1, 1);                                                                            \
    for (int t = 0; t < 14; t++) {                                                          \
        asm volatile("s_barrier" ::: "memory");                                             \
        stage((t + 2) % 3, t + 2);                                                          \
        asm volatile("s_waitcnt vmcnt(12)" ::: "memory");                                   \
        compute(t % 3);                                                                     \
    }                                                                                       \
    asm volatile("s_barrier" ::: "memory");                                                 \
    asm volatile("s_waitcnt vmcnt(6)" ::: "memory");                                        \
    compute(14 % 3);                                                                        \
    asm volatile("s_barrier" ::: "memory");                                                 \
    asm volatile("s_waitcnt vmcnt(0)" ::: "memory");                                        \
    compute(15 % 3);

// ---------------- fused QKV GEMM: [8192 x 3072], segmented epilogue ----------------
__global__ __launch_bounds__(512) void gemm_qkv(const u16t* __restrict__ A,
                                                const u16t* __restrict__ BT,
                                                const float* __restrict__ bq,
                                                const float* __restrict__ bk,
                                                const float* __restrict__ bvv,
                                                u16t* __restrict__ Qh,
                                                u16t* __restrict__ Kh,
                                                u16t* __restrict__ Vt) {
    int bid = blockIdx.x;                        // 768 blocks (64 m x 12 n), tail-free
    int wg = (bid & 7) * 96 + (bid >> 3);        // bijective XCD swizzle (768 % 8 == 0)
    int m0 = (wg / 12) * 128, n0 = (wg % 12) * 256;

    GEMM_CORE_512(A, BT, m0, n0)

    #pragma unroll
    for (int i = 0; i < 4; i++) {
        #pragma unroll
        for (int j = 0; j < 4; j++) {
            int col = n0 + wn * 64 + j * 16 + ln;
            int seg = col >> 10, c1k = col & 1023;
            float bias = seg == 0 ? bq[c1k] : seg == 1 ? bk[c1k] : bvv[c1k];
            int rowb = m0 + wm * 64 + i * 16 + g * 4;
            int b = rowb >> 11, s = rowb & 2047, h = c1k >> 6, hd = c1k & 63;
            if (seg == 0) {
                for (int r = 0; r < 4; r++) {
                    float v = (acc[i][j][r] + bias) * QSCALE;
                    Qh[((size_t)(b * Hh + h) * Ss + s + r) * 64 + hd] = f2bf(v);
                }
            } else if (seg == 1) {
                for (int r = 0; r < 4; r++)
                    Kh[((size_t)(b * Hh + h) * Ss + s + r) * 64 + hd] = f2bf(acc[i][j][r] + bias);
            } else {
                u16t pk4[4];
                for (int r = 0; r < 4; r++) pk4[r] = f2bf(acc[i][j][r] + bias);
                *(ushort4*)(Vt + ((size_t)((b * Hh + h) * 64 + hd) << 11) + s) = *(ushort4*)pk4;
            }
        }
    }
}

// ---------------- output GEMM: d_out[8192 x 1024] fp32 ----------------
__global__ __launch_bounds__(512) void gemm_o(const u16t* __restrict__ A,
                                              const u16t* __restrict__ BT,
                                              const float* __restrict__ bias,
                                              float* __restrict__ outF) {
    int bid = blockIdx.x;                        // 256 blocks (64 m x 4 n), tail-free
    int wg = (bid & 7) * 32 + (bid >> 3);
    int m0 = (wg >> 2) * 128, n0 = (wg & 3) * 256;

    GEMM_CORE_512(A, BT, m0, n0)

    #pragma unroll
    for (int i = 0; i < 4; i++) {
        #pragma unroll
        for (int j = 0; j < 4; j++) {
            int col = n0 + wn * 64 + j * 16 + ln;
            float bv = bias[col];
            int rowb = m0 + wm * 64 + i * 16 + g * 4;
            for (int r = 0; r < 4; r++)
                outF[(size_t)(rowb + r) * Dd + col] = acc[i][j][r] + bv;
        }
    }
}

// ---------------- Flash attention: 8 waves, in-block kv-split, LDS merge ----------------
// Block handles q-tiles (ip, 15-ip) sequentially. Per task (q-tile qx): wave-group 0
// (waves 0-3) scans kv tiles [0, qx], group 1 (waves 4-7) scans [qx+1, 2qx+1].
// Each group has its own K/V double buffer (64KB -> 2 blocks/CU -> 16 waves/CU).
// Group 1 posts unnormalized O/m/l into dead K/V LDS; group 0 combines and writes.
// RULE #20: register chunk indices (dt, rb) are STATIC (from the unrolled loop
// counter); only the LDS ADDRESS carries the XOR rotation (fq = fidx ^ (l31&7)).
__global__ __launch_bounds__(512, 4) void attn(const u16t* __restrict__ Qh,
                                               const u16t* __restrict__ Kh,
                                               const u16t* __restrict__ Vt,
                                               u16t* __restrict__ Ob) {
    __shared__ __align__(16) u16t Ksm[2][2][64 * 64];   // [group][buf] 32KB
    __shared__ __align__(16) u16t Vsm[2][2][64 * 64];   // [group][buf] 32KB
    float*  mergeO  = (float*)&Ksm[0][0][0];            // 32KB alias (dead after scan)
    float2* mergeML = (float2*)&Vsm[0][0][0];           // 1KB alias

    int tid = threadIdx.x, lane = tid & 63, w = tid >> 6;
    int grp = w >> 2, wg = w & 3;
    int l31 = lane & 31, hi = lane >> 5;
    // XCD-clustered: 512 blocks; XCD x hosts bh in [8x, 8x+8)
    int flat = blockIdx.y * 8 + blockIdx.x;
    int xcd = flat & 7, jj = flat >> 3;
    int bh = xcd * 8 + (jj >> 3);
    int ip = jj & 7;

    const u16t* Kb = Kh + (size_t)bh * Ss * 64;
    const u16t* Vb = Vt + (size_t)bh * 64 * Ss;

    int sr0 = wg * 16 + (lane >> 3);
    int sr1 = sr0 + 8;
    int sc0 = (((lane & 7) ^ (sr0 & 7) ^ ((sr0 >> 3) & 3)) * 8);
    int sc1 = (((lane & 7) ^ (sr1 & 7) ^ ((sr1 >> 3) & 3)) * 8);
    const u16t* Kg0 = Kb + (size_t)sr0 * 64 + sc0;
    const u16t* Kg1 = Kb + (size_t)sr1 * 64 + sc1;
    const u16t* Vg0 = Vb + (size_t)sr0 * Ss + sc0;
    const u16t* Vg1 = Vb + (size_t)sr1 * Ss + sc1;

    auto stage = [&](int buf, int t) {
        size_t koff = (size_t)t * 64 * 64;
        size_t voff = (size_t)t * 64;
        __builtin_amdgcn_global_load_lds(Kg0 + koff, &Ksm[grp][buf][(wg * 2 + 0) * 512], 16, 0, 0);
        __builtin_amdgcn_global_load_lds(Kg1 + koff, &Ksm[grp][buf][(wg * 2 + 1) * 512], 16, 0, 0);
        __builtin_amdgcn_global_load_lds(Vg0 + voff, &Vsm[grp][buf][(wg * 2 + 0) * 512], 16, 0, 0);
        __builtin_amdgcn_global_load_lds(Vg1 + voff, &Vsm[grp][buf][(wg * 2 + 1) * 512], 16, 0, 0);
    };

    int swzr = (l31 & 7) ^ ((l31 >> 3) & 3);   // same key for rows l31, 32+l31

    for (int task = 0; task < 2; task++) {
        int qx = task == 0 ? ip : 15 - ip;
        int qb = qx * 128;
        int q0w = qb + wg * 32;
        int qlane = q0w + l31;

        bf16x8 qB[4];
        {
            const u16t* Qp = Qh + ((size_t)bh * Ss + qlane) * 64 + hi * 8;
            #pragma unroll
            for (int ks = 0; ks < 4; ks++)
                qB[ks] = *(const bf16x8*)(Qp + 16 * ks);
        }

        f32x16 oacc[2] = {};
        float m_run = NEG, l_run = 0.f;
        int half = qx + 1;
        int tbase = grp == 0 ? 0 : half;

        stage(0, tbase);
        __syncthreads();

        for (int it = 0; it < half; it++) {
            int cur = it & 1;
            int kv0 = (tbase + it) << 6;
            if (it + 1 < half) stage(cur ^ 1, tbase + it + 1);

            bool active = (kv0 <= q0w + 31);
            if (active) {
                // ---- QK^T (swapped): lane owns one q-column of S^T ----
                f32x16 p0 = {}, p1 = {};
                __builtin_amdgcn_s_setprio(1);
                #pragma unroll
                for (int ks = 0; ks < 4; ks++) {
                    int cc = (2 * ks + hi) ^ swzr;
                    bf16x8 ka0 = *(const bf16x8*)&Ksm[grp][cur][(size_t)l31 * 64 + cc * 8];
                    bf16x8 ka1 = *(const bf16x8*)&Ksm[grp][cur][(size_t)(32 + l31) * 64 + cc * 8];
                    p0 = __builtin_amdgcn_mfma_f32_32x32x16_bf16(ka0, qB[ks], p0, 0, 0, 0);
                    p1 = __builtin_amdgcn_mfma_f32_32x32x16_bf16(ka1, qB[ks], p1, 0, 0, 0);
                }
                __builtin_amdgcn_s_setprio(0);

                if (kv0 + 63 > q0w) {               // causal mask, diagonal tiles only
                    #pragma unroll
                    for (int r = 0; r < 16; r++) {
                        int kvg = kv0 + (r & 3) + 8 * (r >> 2) + 4 * hi;
                        if (kvg > qlane)      p0[r] = NEG;
                        if (kvg + 32 > qlane) p1[r] = NEG;
                    }
                }

                // ---- online softmax, defer-max (THR=10, exp2 domain) ----
                float ma = fmaxf(p0[0], p1[0]), mb = fmaxf(p0[1], p1[1]);
                float mc = fmaxf(p0[2], p1[2]), md = fmaxf(p0[3], p1[3]);
                #pragma unroll
                for (int r = 4; r < 16; r += 4) {
                    ma = fmaxf(ma, fmaxf(p0[r], p1[r]));
                    mb = fmaxf(mb, fmaxf(p0[r + 1], p1[r + 1]));
                    mc = fmaxf(mc, fmaxf(p0[r + 2], p1[r + 2]));
                    md = fmaxf(md, fmaxf(p0[r + 3], p1[r + 3]));
                }
                float mt = fmaxf(fmaxf(ma, mb), fmaxf(mc, md));
                mt = fmaxf(mt, __shfl_xor(mt, 32));
                if (__any(mt > m_run + 10.0f)) {
                    float mn = fmaxf(m_run, mt);
                    float al = __builtin_exp2f(m_run - mn);
                    m_run = mn;
                    l_run *= al;
                    #pragma unroll
                    for (int r = 0; r < 16; r++) { oacc[0][r] *= al; oacc[1][r] *= al; }
                }
                #pragma unroll
                for (int r = 0; r < 16; r++) {
                    p0[r] = __builtin_exp2f(p0[r] - m_run);
                    p1[r] = __builtin_exp2f(p1[r] - m_run);
                }
                float sa = 0.f, sb = 0.f, sc2 = 0.f, sd = 0.f;
                #pragma unroll
                for (int r = 0; r < 16; r += 4) {
                    sa += p0[r] + p1[r];
                    sb += p0[r + 1] + p1[r + 1];
                    sc2 += p0[r + 2] + p1[r + 2];
                    sd += p0[r + 3] + p1[r + 3];
                }
                float rsum = (sa + sb) + (sc2 + sd);
                rsum += __shfl_xor(rsum, 32);
                l_run += rsum;

                // ---- pack P -> PV B-fragments: 16 cvt_pk + 8 permlane32_swap ----
                bf16x8 pb[4];
                {
                    uint32_t c0, c1, c2, c3;
                    asm("v_cvt_pk_bf16_f32 %0, %1, %2" : "=v"(c0) : "v"(p0[0]), "v"(p0[1]));
                    asm("v_cvt_pk_bf16_f32 %0, %1, %2" : "=v"(c1) : "v"(p0[2]), "v"(p0[3]));
                    asm("v_cvt_pk_bf16_f32 %0, %1, %2" : "=v"(c2) : "v"(p0[4]), "v"(p0[5]));
                    asm("v_cvt_pk_bf16_f32 %0, %1, %2" : "=v"(c3) : "v"(p0[6]), "v"(p0[7]));
                    asm volatile("v_permlane32_swap_b32 %0, %1" : "+v"(c0), "+v"(c2));
                    asm volatile("v_permlane32_swap_b32 %0, %1" : "+v"(c1), "+v"(c3));
                    uint32_t w4[4] = {c0, c1, c2, c3};
                    pb[0] = *(bf16x8*)w4;
                    uint32_t d0, d1, d2, d3;
                    asm("v_cvt_pk_bf16_f32 %0, %1, %2" : "=v"(d0) : "v"(p0[8]),  "v"(p0[9]));
                    asm("v_cvt_pk_bf16_f32 %0, %1, %2" : "=v"(d1) : "v"(p0[10]), "v"(p0[11]));
                    asm("v_cvt_pk_bf16_f32 %0, %1, %2" : "=v"(d2) : "v"(p0[12]), "v"(p0[13]));
                    asm("v_cvt_pk_bf16_f32 %0, %1, %2" : "=v"(d3) : "v"(p0[14]), "v"(p0[15]));
                    asm volatile("v_permlane32_swap_b32 %0, %1" : "+v"(d0), "+v"(d2));
                    asm volatile("v_permlane32_swap_b32 %0, %1" : "+v"(d1), "+v"(d3));
                    uint32_t w5[4] = {d0, d1, d2, d3};
                    pb[1] = *(bf16x8*)w5;
                    uint32_t e0, e1, e2, e3;
                    asm("v_cvt_pk_bf16_f32 %0, %1, %2" : "=v"(e0) : "v"(p1[0]), "v"(p1[1]));
                    asm("v_cvt_pk_bf16_f32 %0, %1, %2" : "=v"(e1) : "v"(p1[2]), "v"(p1[3]));
                    asm("v_cvt_pk_bf16_f32 %0, %1, %2" : "=v"(e2) : "v"(p1[4]), "v"(p1[5]));
                    asm("v_cvt_pk_bf16_f32 %0, %1, %2" : "=v"(e3) : "v"(p1[6]), "v"(p1[7]));
                    asm volatile("v_permlane32_swap_b32 %0, %1" : "+v"(e0), "+v"(e2));
                    asm volatile("v_permlane32_swap_b32 %0, %1" : "+v"(e1), "+v"(e3));
                    uint32_t w6[4] = {e0, e1, e2, e3};
                    pb[2] = *(bf16x8*)w6;
                    uint32_t f0, f1, f2, f3;
                    asm("v_cvt_pk_bf16_f32 %0, %1, %2" : "=v"(f0) : "v"(p1[8]),  "v"(p1[9]));
                    asm("v_cvt_pk_bf16_f32 %0, %1, %2" : "=v"(f1) : "v"(p1[10]), "v"(p1[11]));
                    asm("v_cvt_pk_bf16_f32 %0, %1, %2" : "=v"(f2) : "v"(p1[12]), "v"(p1[13]));
                    asm("v_cvt_pk_bf16_f32 %0, %1, %2" : "=v"(f3) : "v"(p1[14]), "v"(p1[15]));
                    asm volatile("v_permlane32_swap_b32 %0, %1" : "+v"(f0), "+v"(f2));
                    asm volatile("v_permlane32_swap_b32 %0, %1" : "+v"(f1), "+v"(f3));
                    uint32_t w7[4] = {f0, f1, f2, f3};
                    pb[3] = *(bf16x8*)w7;
                }

                // ---- PV (swapped): O^T[d][q] += V^T[d][kv] @ P^T[kv][q] ----
                __builtin_amdgcn_s_setprio(1);
                #pragma unroll
                for (int dt = 0; dt < 2; dt++) {
                    int drow = dt * 32 + l31;
                    #pragma unroll
                    for (int ks = 0; ks < 4; ks++) {
                        int cc = (2 * ks + hi) ^ swzr;
                        bf16x8 va = *(const bf16x8*)&Vsm[grp][cur][(size_t)drow * 64 + cc * 8];
                        oacc[dt] = __builtin_amdgcn_mfma_f32_32x32x16_bf16(va, pb[ks], oacc[dt], 0, 0, 0);
                    }
                }
                __builtin_amdgcn_s_setprio(0);
            }
            __syncthreads();
        }

        // ---- merge: group 1 posts partials into dead K/V LDS (STATIC reg indices) ----
        if (grp == 1) {
            if (hi == 0) {
                float2 v; v.x = m_run; v.y = l_run;
                mergeML[wg * 32 + l31] = v;
            }
            #pragma unroll
            for (int fidx = 0; fidx < 8; fidx++) {
                const int dt = fidx >> 2, rb = (fidx & 3) * 4;   // static
                int fq = fidx ^ (l31 & 7);                        // address-only rotation
                f32x4 ch;
                #pragma unroll
                for (int j = 0; j < 4; j++) ch[j] = oacc[dt][rb + j];
                *(f32x4*)(mergeO + ((size_t)(wg * 512 + l31 * 16 + hi * 8 + fq) << 2)) = ch;
            }
        }
        __syncthreads();

        if (grp == 0) {
            float2 ml1 = mergeML[wg * 32 + l31];
            float mmax = fmaxf(m_run, ml1.x);
            float e0 = __builtin_exp2f(m_run - mmax);
            float e1 = __builtin_exp2f(ml1.x - mmax);
            float linv = 1.0f / (l_run * e0 + ml1.y * e1);
            float f0 = e0 * linv, f1 = e1 * linv;
            #pragma unroll
            for (int fidx = 0; fidx < 8; fidx++) {
                const int dt = fidx >> 2, rb = (fidx & 3) * 4;   // static
                int fq = fidx ^ (l31 & 7);
                f32x4 c1 = *(const f32x4*)(mergeO + ((size_t)(wg * 512 + l31 * 16 + hi * 8 + fq) << 2));
                #pragma unroll
                for (int j = 0; j < 4; j++)
                    oacc[dt][rb + j] = oacc[dt][rb + j] * f0 + c1[j] * f1;
            }
        }
        __syncthreads();   // merge reads done before next task restages LDS

        if (grp == 0) {
            int b = bh >> 4, h = bh & 15;
            u16t* Op = Ob + ((size_t)(b * Ss + qlane)) * Dd + h * 64;
            #pragma unroll
            for (int dt = 0; dt < 2; dt++)
                #pragma unroll
                for (int rq = 0; rq < 4; rq++) {
                    u16t pk4[4];
                    #pragma unroll
                    for (int j = 0; j < 4; j++) pk4[j] = f2bf(oacc[dt][rq * 4 + j]);
                    int d0 = dt * 32 + rq * 8 + hi * 4;
                    *(ushort4*)(Op + d0) = *(ushort4*)pk4;
                }
        }
    }
}

extern "C" void kernel_launch(void* const* d_in, const int* in_sizes, int n_in,
                              void* d_out, int out_size, void* d_ws, size_t ws_size,
                              hipStream_t stream) {
    const float* x  = (const float*)d_in[0];
    const float* Wq = (const float*)d_in[1];
    const float* bq = (const float*)d_in[2];
    const float* Wk = (const float*)d_in[3];
    const float* bk = (const float*)d_in[4];
    const float* Wv = (const float*)d_in[5];
    const float* bv = (const float*)d_in[6];
    const float* Wo = (const float*)d_in[7];
    const float* bo = (const float*)d_in[8];

    char* ws = (char*)d_ws;
    size_t off = 0;
    auto alloc = [&](size_t bytes) { char* p = ws + off; off += (bytes + 255) & ~(size_t)255; return p; };
    u16t* xb    = (u16t*)alloc((size_t)Mrows * Dd * 2);
    u16t* WqkvT = (u16t*)alloc((size_t)3 * Dd * Dd * 2);
    u16t* WoT   = (u16t*)alloc((size_t)Dd * Dd * 2);
    u16t* Qh    = (u16t*)alloc((size_t)Mrows * Dd * 2);
    u16t* Kh    = (u16t*)alloc((size_t)Mrows * Dd * 2);
    u16t* Vtp   = (u16t*)alloc((size_t)Mrows * Dd * 2);
    u16t* Ob    = (u16t*)alloc((size_t)Mrows * Dd * 2);

    int nx = Mrows * Dd;
    cvt_bf16<<<nx / (256 * 4), 256, 0, stream>>>(x, xb, nx);
    dim3 tg(16, 16, 4);
    transpose_cvt4<<<tg, 256, 0, stream>>>(Wq, Wk, Wv, Wo, WqkvT, WoT);

    gemm_qkv<<<768, 512, 0, stream>>>(xb, WqkvT, bq, bk, bv, Qh, Kh, Vtp);

    dim3 ga(8, Bb * Hh);              // 512 blocks x 8 waves, in-block kv-split
    attn<<<ga, 512, 0, stream>>>(Qh, Kh, Vtp, Ob);

    gemm_o<<<256, 512, 0, stream>>>(Ob, WoT, bo, (float*)d_out);
}